// Round 10
// baseline (29.739 us; speedup 1.0000x reference)
//
#include <hip/hip_runtime.h>

#define Nn 8
#define Cc 4
#define Hh 256
#define Ww 256

typedef unsigned short u16;
typedef u16 u16x4 __attribute__((ext_vector_type(4)));
typedef unsigned long long u64;

// Workspace layout (bytes): partials only
#define OFF_PART 0

// ---------------------------------------------------------------------------
// Merged kernel (R9 body + runtime npass diagnostic loop).
// npass=2, scale=0.5f -> bitwise-identical result to R9 (2*x then *0.5 exact);
// the marginal cost of pass 2 isolates compute/LDS/stall from first-touch
// memory + launch overhead. Logits loaded once (registers, reused).
// ---------------------------------------------------------------------------
__global__ __launch_bounds__(256) void merged_kernel(
    const int* __restrict__ tgt, const float* __restrict__ in,
    float* __restrict__ partials, int npass, float scale) {
  __shared__ u64 smp[32][4][6];   // [row][class][guard,w0..w3,guard] = 6 KB
  __shared__ u16x4 s2[32][64];    // sat g^2, row r <-> k = i0-8+r   = 16 KB
  __shared__ float s_w[4];
  const int bid = blockIdx.x;     // n*64 + it*4 + jt  (8*16*4 = 512)
  const int n = bid >> 6;
  const int it = (bid >> 2) & 15;
  const int jt = bid & 3;
  const int i0 = it * 16, j0 = jt * 64;
  const int tid = threadIdx.x;
  const int lane = tid & 63;
  const int w = tid >> 6;         // wave id 0..3
  const int jj = tid & 63;
  const int j = j0 + jj;

  // ---- logit loads once, up front (registers reused across passes) ----
  const long cs = (long)Hh * Ww;
  const float* lp = in + ((long)(n * Cc) * Hh + (i0 + w * 4)) * Ww + j;
  float x[4][4];                  // [m][c] — all indices compile-time
#pragma unroll
  for (int c = 0; c < 4; ++c)
#pragma unroll
    for (int m = 0; m < 4; ++m) x[m][c] = lp[c * cs + m * Ww];

  // ---- guards (once; mask builds only touch words 1..4) ----
  {
    const int r = tid >> 3, c = (tid >> 1) & 3, g01 = (tid & 1) * 5;
    smp[r][c][g01] = 0ull;
  }

  float contrib = 0.0f;
  for (int pass = 0; pass < npass; ++pass) {
    // ---- 2. mask build: wave w -> rows w*8 .. w*8+7 ----
    // (smp last read in phase 3 of prev pass, gated by post-ph3 barrier)
#pragma unroll
    for (int rr = 0; rr < 8; ++rr) {
      const int r = w * 8 + rr;
      const int k = i0 - 8 + r;
      if (k >= 0 && k < Hh) {     // wave-uniform
        const int rowOff = (n * Hh + k) * Ww;
        const int t0 = tgt[rowOff + lane];
        const int t1 = tgt[rowOff + lane + 64];
        const int t2 = tgt[rowOff + lane + 128];
        const int t3 = tgt[rowOff + lane + 192];
#pragma unroll
        for (int c = 0; c < Cc; ++c) {
          const u64 m0 = __ballot(t0 == c);
          const u64 m1 = __ballot(t1 == c);
          const u64 m2 = __ballot(t2 == c);
          const u64 m3 = __ballot(t3 == c);
          if (lane == 0) {
            smp[r][c][1] = m0; smp[r][c][2] = m1;
            smp[r][c][3] = m2; smp[r][c][4] = m3;
          }
        }
      }
    }
    __syncthreads();  // gates: smp writes; also s2 reads of prev pass done

    // ---- 3. g^2 compute: thread (w, jj) handles rows w*8+q ----
    const u16 SENT = 0xFE00;      // 65024; +dd(<=64) < 65536 no wrap
#pragma unroll
    for (int q = 0; q < 8; ++q) {
      const int r = w * 8 + q;
      const int k = i0 - 8 + r;
      u16x4 sq = {SENT, SENT, SENT, SENT};
      if (k >= 0 && k < Hh) {     // wave-uniform
        const int S = j + 32;     // abs bitspace: orig bit x at 64+x
        const int word = S >> 6;  // 0..4
        const int sh = S & 63;
        u16 dv[4];
#pragma unroll
        for (int c = 0; c < Cc; ++c) {
          const u64* M = smp[r][c];
          const u64 lo = M[word];
          const u64 hi = M[word + 1];
          const u64 win = sh ? ((lo >> sh) | (hi << (64 - sh))) : lo;
          const u64 ml = win & 0x1FFFFFFFFull;   // bits [j-32, j]
          const u64 mr = win >> 32;              // bits [j, j+31]
          int dd;
          if (ml | mr) {
            const int dl = ml ? (__builtin_clzll(ml) - 31) : 512;
            const int dr = mr ? (int)__builtin_ctzll(mr) : 512;
            dd = min(dl, dr);
          } else {
            // exact rare fallback: full 4-word scan both directions
            int dl = 512, dr = 512;
#pragma unroll
            for (int w2 = 3; w2 >= 0; --w2) {
              if (w2 * 64 <= j) {
                u64 m = M[1 + w2];
                if (w2 == (j >> 6)) {
                  const int r6 = j & 63;
                  m &= (r6 == 63) ? ~0ull : ((1ull << (r6 + 1)) - 1ull);
                }
                if (m && dl == 512)
                  dl = j - (w2 * 64 + 63 - __builtin_clzll(m));
              }
            }
#pragma unroll
            for (int w2 = 0; w2 < 4; ++w2) {
              if (w2 * 64 + 63 >= j) {
                u64 m = M[1 + w2];
                if (w2 == (j >> 6)) m &= ~((1ull << (j & 63)) - 1ull);
                if (m && dr == 512)
                  dr = w2 * 64 + (int)__builtin_ctzll(m) - j;
              }
            }
            dd = min(min(dl, dr), 512);
          }
          dd = min(dd, 255);      // sat: only perturbs values > 81
          dv[c] = (u16)(dd * dd);
        }
        sq.x = dv[0]; sq.y = dv[1]; sq.z = dv[2]; sq.w = dv[3];
      }
      s2[r][jj] = sq;
    }
    __syncthreads();

    // ---- 4. sliding column window: rows w*4 .. w*4+19 feed acc[0..3] ----
    u16x4 acc[4];
#pragma unroll
    for (int m = 0; m < 4; ++m)
      acc[m] = (u16x4){0xFFFF, 0xFFFF, 0xFFFF, 0xFFFF};
#pragma unroll
    for (int rr = 0; rr < 20; ++rr) {
      const u16x4 val = s2[w * 4 + rr][jj];
#pragma unroll
      for (int m = 0; m < 4; ++m) {
        const int kq = rr - m;
        if (kq >= 0 && kq <= 16) {  // compile-time predicate
          const int dd = (8 - kq) * (8 - kq);
          const u16x4 ddv = {(u16)dd, (u16)dd, (u16)dd, (u16)dd};
          acc[m] = __builtin_elementwise_min(acc[m], val + ddv);
        }
      }
    }

    // ---- 5+6. exactness check, softmax, loss ----
#pragma unroll
    for (int m = 0; m < 4; ++m) {
      const int i = i0 + w * 4 + m;
      int d0 = acc[m].x, d1 = acc[m].y, d2 = acc[m].z, d3 = acc[m].w;
      // excluded k have (i-k)^2 >= 81: min <= 81 -> provably exact.
      if (max(max(d0, d1), max(d2, d3)) > 81) {  // P ~ 1e-18, exact if taken
        d0 = 0x7fffffff; d1 = 0x7fffffff; d2 = 0x7fffffff; d3 = 0x7fffffff;
        const int* tp = tgt + n * (Hh * Ww);
        for (int p = 0; p < Hh * Ww; ++p) {
          const int t = tp[p];
          const int dy = i - (p >> 8);
          const int dx = j - (p & 255);
          const int dd2 = dy * dy + dx * dx;
          d0 = (t == 0) ? min(d0, dd2) : d0;
          d1 = (t == 1) ? min(d1, dd2) : d1;
          d2 = (t == 2) ? min(d2, dd2) : d2;
          d3 = (t == 3) ? min(d3, dd2) : d3;
        }
      }
      const float f0 = (float)d0, f1 = (float)d1;  // exact: < 2^24
      const float f2 = (float)d2, f3 = (float)d3;
      const float mx = fmaxf(fmaxf(x[m][0], x[m][1]),
                             fmaxf(x[m][2], x[m][3]));
      const float e0 = __expf(x[m][0] - mx), e1 = __expf(x[m][1] - mx);
      const float e2 = __expf(x[m][2] - mx), e3 = __expf(x[m][3] - mx);
      const float rs = 1.0f / (e0 + e1 + e2 + e3);
      const float p0 = e0 * rs, p1 = e1 * rs, p2 = e2 * rs, p3 = e3 * rs;
      // own-class d is exactly 0; exclude it for dbar
      const int q0 = (d0 == 0) ? 0x7fffffff : d0;
      const int q1 = (d1 == 0) ? 0x7fffffff : d1;
      const int q2 = (d2 == 0) ? 0x7fffffff : d2;
      const int q3 = (d3 == 0) ? 0x7fffffff : d3;
      const float dbar = (float)min(min(q0, q1), min(q2, q3));
      const float pt = (d0 == 0) ? p0 : (d1 == 0) ? p1 : (d2 == 0) ? p2 : p3;
      contrib += pt * sqrtf(dbar) -
                 (p0 * sqrtf(f0) + p1 * sqrtf(f1) +
                  p2 * sqrtf(f2) + p3 * sqrtf(f3));
    }
  }

  // ---- block reduction (deterministic fixed order) ----
#pragma unroll
  for (int off = 32; off > 0; off >>= 1) contrib += __shfl_down(contrib, off);
  if (lane == 0) s_w[w] = contrib;
  __syncthreads();
  if (tid == 0) {
    partials[bid] = ((s_w[0] + s_w[1]) + (s_w[2] + s_w[3])) * scale;
  }
}

// ---------------------------------------------------------------------------
// Finalize: deterministic reduction of 512 partials + scaling
// ---------------------------------------------------------------------------
__global__ __launch_bounds__(256) void finalize_kernel(
    const float* __restrict__ partials, float* __restrict__ out) {
  __shared__ float s_red[256];
  const int tid = threadIdx.x;
  const float v0 = partials[tid];
  const float v1 = partials[tid + 256];
  s_red[tid] = v0 + v1;
  __syncthreads();
  for (int st = 128; st > 0; st >>= 1) {
    if (tid < st) s_red[tid] += s_red[tid + st];
    __syncthreads();
  }
  if (tid == 0)
    out[0] = s_red[0] / (float)(Cc * Nn) / (65536.0f + 1e-6f);
}

extern "C" void kernel_launch(void* const* d_in, const int* in_sizes, int n_in,
                              void* d_out, int out_size, void* d_ws, size_t ws_size,
                              hipStream_t stream) {
  const float* input = (const float*)d_in[0];   // [8,4,256,256] fp32 logits
  const int* target = (const int*)d_in[1];      // [8,256,256] int32
  float* out = (float*)d_out;                   // scalar fp32
  float* partials = (float*)((char*)d_ws + OFF_PART);

  merged_kernel<<<dim3(512), dim3(256), 0, stream>>>(target, input, partials,
                                                     2, 0.5f);
  finalize_kernel<<<dim3(1), dim3(256), 0, stream>>>(partials, out);
}

// Round 11
// 16.663 us; speedup vs baseline: 1.7847x; 1.7847x over previous
//
#include <hip/hip_runtime.h>

#define Nn 8
#define Cc 4
#define Hh 256
#define Ww 256

typedef unsigned short u16;
typedef u16 u16x4 __attribute__((ext_vector_type(4)));
typedef unsigned long long u64;

// Workspace layout (bytes): partials only
#define OFF_PART 0

// ---------------------------------------------------------------------------
// Merged kernel, 1 pixel/thread: block = 1024 thr (16 waves) on a 16i x 64j
// tile; grid 512 -> 8 waves/SIMD, 32 waves/CU (2 blocks x 22.6 KB LDS).
//  1. 4 logit loads up front (in flight through phases 2-3)
//  2. ballot-built 256-bit class masks for the 32 g-rows (8-row halo)
//  3. per (row, j): row distance via funnel/clz window over [-32,+31],
//     CLAMPED AT 10. Exactness: the final test is `min d2 <= 81`; any g > 9
//     has g^2 >= 100, so a clamped g can never win a <=81 min. Hence
//     computed-min <= 81  <=>  exact; computed-min > 81 <=> true-min > 81
//     (identical trigger as unclamped) -> phase-5 EXACT brute-force fallback.
//  4. 17-tap packed-u16 column window (radius 8), 1 px/thread
//  5. exactness check (fallback P ~ 1e-26 on random data, exact if taken)
//  6. __expf softmax + loss + deterministic two-level reduction
// ---------------------------------------------------------------------------
__global__ __launch_bounds__(1024) void merged_kernel(
    const int* __restrict__ tgt, const float* __restrict__ in,
    float* __restrict__ partials) {
  __shared__ u64 smp[32][4][6];   // [row][class][guard,w0..w3,guard] = 6 KB
  __shared__ u16x4 s2[32][64];    // sat g^2, row r <-> k = i0-8+r   = 16 KB
  __shared__ float s_w[16];
  const int bid = blockIdx.x;     // n*64 + it*4 + jt  (8*16*4 = 512)
  const int n = bid >> 6;
  const int it = (bid >> 2) & 15;
  const int jt = bid & 3;
  const int i0 = it * 16, j0 = jt * 64;
  const int tid = threadIdx.x;
  const int lane = tid & 63;
  const int w = tid >> 6;         // wave 0..15; pixel row i = i0 + w
  const int jj = lane;
  const int j = j0 + jj;
  const int i = i0 + w;

  // ---- 1. logit loads (4, independent; hidden under phases 2-3) ----
  const long cs = (long)Hh * Ww;
  const float* lp = in + ((long)(n * Cc) * Hh + i) * Ww + j;
  const float x0 = lp[0];
  const float x1 = lp[cs];
  const float x2 = lp[2 * cs];
  const float x3 = lp[3 * cs];

  // ---- guards (idx 0 and 5): 32*4*2 = 256 writes ----
  if (tid < 256) {
    const int r = tid >> 3, c = (tid >> 1) & 3, g01 = (tid & 1) * 5;
    smp[r][c][g01] = 0ull;
  }

  // ---- 2. mask build: wave w -> rows 2w, 2w+1 ----
#pragma unroll
  for (int rr = 0; rr < 2; ++rr) {
    const int r = 2 * w + rr;
    const int k = i0 - 8 + r;
    if (k >= 0 && k < Hh) {       // wave-uniform
      const int rowOff = (n * Hh + k) * Ww;
      const int t0 = tgt[rowOff + lane];
      const int t1 = tgt[rowOff + lane + 64];
      const int t2 = tgt[rowOff + lane + 128];
      const int t3 = tgt[rowOff + lane + 192];
#pragma unroll
      for (int c = 0; c < Cc; ++c) {
        const u64 m0 = __ballot(t0 == c);
        const u64 m1 = __ballot(t1 == c);
        const u64 m2 = __ballot(t2 == c);
        const u64 m3 = __ballot(t3 == c);
        if (lane == 0) {
          smp[r][c][1] = m0; smp[r][c][2] = m1;
          smp[r][c][3] = m2; smp[r][c][4] = m3;
        }
      }
    }
  }
  __syncthreads();

  // ---- 3. g^2 (clamped at 10): thread (w, jj) handles rows 2w, 2w+1 ----
  const u16 SENT = 0xFE00;        // 65024; +dd(<=64) < 65536, no wrap
#pragma unroll
  for (int rr = 0; rr < 2; ++rr) {
    const int r = 2 * w + rr;
    const int k = i0 - 8 + r;
    u16x4 sq = {SENT, SENT, SENT, SENT};
    if (k >= 0 && k < Hh) {       // wave-uniform
      const int S = j + 32;       // padded bitspace: orig bit x at 64+x
      const int word = S >> 6;    // 0..4
      const int sh = S & 63;
      u16 dv[4];
#pragma unroll
      for (int c = 0; c < Cc; ++c) {
        const u64* M = smp[r][c];
        const u64 lo = M[word];
        const u64 hi = M[word + 1];
        const u64 win = sh ? ((lo >> sh) | (hi << (64 - sh))) : lo;
        const u64 ml = win & 0x1FFFFFFFFull;   // bits [j-32, j]
        const u64 mr = win >> 32;              // bits [j, j+31]
        const int dl = ml ? (__builtin_clzll(ml) - 31) : 512;
        const int dr = mr ? (int)__builtin_ctzll(mr) : 512;
        const int dd = min(min(dl, dr), 10);   // clamp 10 (see header proof)
        dv[c] = (u16)(dd * dd);
      }
      sq.x = dv[0]; sq.y = dv[1]; sq.z = dv[2]; sq.w = dv[3];
    }
    s2[r][jj] = sq;
  }
  __syncthreads();

  // ---- 4. 17-tap column window, 1 px/thread: rows w .. w+16 ----
  u16x4 acc = {0xFFFF, 0xFFFF, 0xFFFF, 0xFFFF};
#pragma unroll
  for (int kq = 0; kq <= 16; ++kq) {
    const int dd = (8 - kq) * (8 - kq);       // compile-time constant
    const u16x4 ddv = {(u16)dd, (u16)dd, (u16)dd, (u16)dd};
    const u16x4 t = s2[w + kq][jj] + ddv;     // b64 read + 2x pk_add
    acc = __builtin_elementwise_min(acc, t);  // 2x pk_min
  }
  int d0 = acc.x, d1 = acc.y, d2 = acc.z, d3 = acc.w;

  // ---- 5. exactness check; rare EXACT brute-force fallback ----
  if (max(max(d0, d1), max(d2, d3)) > 81) {   // P ~ 1e-26, exact if taken
    d0 = 0x7fffffff; d1 = 0x7fffffff; d2 = 0x7fffffff; d3 = 0x7fffffff;
    const int* tp = tgt + n * (Hh * Ww);
    for (int p = 0; p < Hh * Ww; ++p) {
      const int t = tp[p];
      const int dy = i - (p >> 8);
      const int dx = j - (p & 255);
      const int dd2 = dy * dy + dx * dx;
      d0 = (t == 0) ? min(d0, dd2) : d0;
      d1 = (t == 1) ? min(d1, dd2) : d1;
      d2 = (t == 2) ? min(d2, dd2) : d2;
      d3 = (t == 3) ? min(d3, dd2) : d3;
    }
  }

  // ---- 6. softmax + loss ----
  const float f0 = (float)d0, f1 = (float)d1;  // exact: < 2^24
  const float f2 = (float)d2, f3 = (float)d3;
  const float mx = fmaxf(fmaxf(x0, x1), fmaxf(x2, x3));
  const float e0 = __expf(x0 - mx), e1 = __expf(x1 - mx);
  const float e2 = __expf(x2 - mx), e3 = __expf(x3 - mx);
  const float rs = 1.0f / (e0 + e1 + e2 + e3);
  const float p0 = e0 * rs, p1 = e1 * rs, p2 = e2 * rs, p3 = e3 * rs;
  // own-class d is exactly 0; exclude it for dbar
  const int q0 = (d0 == 0) ? 0x7fffffff : d0;
  const int q1 = (d1 == 0) ? 0x7fffffff : d1;
  const int q2 = (d2 == 0) ? 0x7fffffff : d2;
  const int q3 = (d3 == 0) ? 0x7fffffff : d3;
  const float dbar = (float)min(min(q0, q1), min(q2, q3));
  const float pt = (d0 == 0) ? p0 : (d1 == 0) ? p1 : (d2 == 0) ? p2 : p3;
  float contrib = pt * sqrtf(dbar) -
                  (p0 * sqrtf(f0) + p1 * sqrtf(f1) +
                   p2 * sqrtf(f2) + p3 * sqrtf(f3));

  // ---- block reduction (deterministic fixed order) ----
#pragma unroll
  for (int off = 32; off > 0; off >>= 1) contrib += __shfl_down(contrib, off);
  if (lane == 0) s_w[w] = contrib;
  __syncthreads();
  if (tid == 0) {
    float v = 0.0f;
#pragma unroll
    for (int q = 0; q < 16; ++q) v += s_w[q];
    partials[bid] = v;            // plain store (no fence/ticket: R7 lesson)
  }
}

// ---------------------------------------------------------------------------
// Finalize: deterministic reduction of 512 partials + scaling
// ---------------------------------------------------------------------------
__global__ __launch_bounds__(256) void finalize_kernel(
    const float* __restrict__ partials, float* __restrict__ out) {
  __shared__ float s_red[256];
  const int tid = threadIdx.x;
  const float v0 = partials[tid];
  const float v1 = partials[tid + 256];
  s_red[tid] = v0 + v1;
  __syncthreads();
  for (int st = 128; st > 0; st >>= 1) {
    if (tid < st) s_red[tid] += s_red[tid + st];
    __syncthreads();
  }
  if (tid == 0)
    out[0] = s_red[0] / (float)(Cc * Nn) / (65536.0f + 1e-6f);
}

extern "C" void kernel_launch(void* const* d_in, const int* in_sizes, int n_in,
                              void* d_out, int out_size, void* d_ws, size_t ws_size,
                              hipStream_t stream) {
  const float* input = (const float*)d_in[0];   // [8,4,256,256] fp32 logits
  const int* target = (const int*)d_in[1];      // [8,256,256] int32
  float* out = (float*)d_out;                   // scalar fp32
  float* partials = (float*)((char*)d_ws + OFF_PART);

  merged_kernel<<<dim3(512), dim3(1024), 0, stream>>>(target, input, partials);
  finalize_kernel<<<dim3(1), dim3(256), 0, stream>>>(partials, out);
}